// Round 5
// baseline (1049.895 us; speedup 1.0000x reference)
//
#include <hip/hip_runtime.h>
#include <cstdint>
#include <cstddef>

// Problem constants
#define NEXP 8
#define NTOK 8192           // B*S = 4*2048
#define DMODEL 1024
#define DFFN 4096
#define CAP 17408           // 16384 assignments + 8*128 padding capacity
#define MTILES (CAP / 128)  // 136 == 17*8 -> flat%8 == g%8 (XCD affinity)

typedef __bf16 bf16;
typedef bf16 bf16x8 __attribute__((ext_vector_type(8)));
typedef float f32x4 __attribute__((ext_vector_type(4)));

// Fragment-major (FM) layout for an R x K bf16 matrix (R mult of 16, K mult of 32):
//   elem(r,k) -> (((r>>4)*KB + (k>>5))*64 + ((k>>3)&3)*16 + (r&15))*8 + (k&7),  KB=K/32
// A wave's MFMA fragment (16 rows x 32 k) is then 64 lanes x 16 B, lane-consecutive.

// ---------------- workspace layout (bytes) ----------------
static constexpr size_t OFF_HDR  = 0;                        // 64 ints
static constexpr size_t OFF_CNTH = 4096;                     // int[2048*8]
static constexpr size_t OFF_AMH  = OFF_CNTH + 65536;
static constexpr size_t OFF_PSH  = OFF_AMH + 65536;
static constexpr size_t OFF_TOKE = OFF_PSH + 65536;          // int[2*NTOK]
static constexpr size_t OFF_TOKG = OFF_TOKE + 65536;         // float[2*NTOK]
static constexpr size_t OFF_TOKS = OFF_TOKG + 65536;         // int[2*NTOK]
static constexpr size_t OFF_BB   = OFF_TOKS + 65536;         // int[2048*8]
static constexpr size_t OFF_INV  = OFF_BB + 65536;           // int[CAP] slot->token (-1 = pad)
static constexpr size_t OFF_XG   = OFF_INV + 73728;          // bf16[CAP*DMODEL]  (FM)
static constexpr size_t OFF_W1B  = OFF_XG  + (size_t)CAP * DMODEL * 2;   // FM
static constexpr size_t OFF_W2B  = OFF_W1B + (size_t)NEXP * DFFN * DMODEL * 2;
static constexpr size_t OFF_H    = OFF_W2B + (size_t)NEXP * DMODEL * DFFN * 2; // FM
static constexpr size_t OFF_O    = OFF_H   + (size_t)CAP * DFFN * 2;     // f32 row-major

// ---------------- small kernels ----------------

__global__ void k_fillm1(int4* __restrict__ p) {
    p[blockIdx.x * 256 + threadIdx.x] = make_int4(-1, -1, -1, -1);
}

// f32 row-major [gridDim.x*16][K] -> bf16 fragment-major, via LDS transpose staging
template <int K>
__global__ void k_cvt_fm(const float* __restrict__ w, bf16* __restrict__ wfm) {
    constexpr int CB = K / 128;
    __shared__ float ld[16][136];
    int t = threadIdx.x;
    int row = t >> 4, seg = t & 15;
    int kbl = t >> 6, lane = t & 63, quad = lane >> 4, fr = lane & 15;
    const float* src = w + (size_t)(blockIdx.x * 16 + row) * K + seg * 8;
    bf16* dstg = wfm + (size_t)blockIdx.x * 16 * K + lane * 8;
    for (int cb = 0; cb < CB; cb++) {
        const float4* s = (const float4*)(src + cb * 128);
        float4 u = s[0], v = s[1];
        *(float4*)&ld[row][seg * 8] = u;
        *(float4*)&ld[row][seg * 8 + 4] = v;
        __syncthreads();
        float4 a = *(const float4*)&ld[fr][kbl * 32 + quad * 8];
        float4 b = *(const float4*)&ld[fr][kbl * 32 + quad * 8 + 4];
        bf16x8 pk;
        pk[0] = (bf16)a.x; pk[1] = (bf16)a.y; pk[2] = (bf16)a.z; pk[3] = (bf16)a.w;
        pk[4] = (bf16)b.x; pk[5] = (bf16)b.y; pk[6] = (bf16)b.z; pk[7] = (bf16)b.w;
        *(bf16x8*)(dstg + (size_t)(cb * 4 + kbl) * 512) = pk;
        __syncthreads();
    }
}

// wave-per-token gating: fp32 logits, top-2, full softmax partials, argmax hist
__global__ void k_gate(const float* __restrict__ x, const float* __restrict__ gwt,
                       int* __restrict__ cnth, int* __restrict__ amh, float* __restrict__ psh,
                       int* __restrict__ toke, float* __restrict__ tokg) {
    int tid = threadIdx.x, w = tid >> 6, lane = tid & 63;
    int t = blockIdx.x * 4 + w;
    __shared__ int s_cnt[8]; __shared__ int s_am[8]; __shared__ float s_ps[8];
    if (tid < 8) { s_cnt[tid] = 0; s_am[tid] = 0; s_ps[tid] = 0.f; }
    __syncthreads();
    float acc[8] = {0.f,0.f,0.f,0.f,0.f,0.f,0.f,0.f};
    const float4* xr = (const float4*)(x + (size_t)t * DMODEL);
#pragma unroll
    for (int c = 0; c < 4; c++) {
        float4 xv = xr[c * 64 + lane];
#pragma unroll
        for (int e = 0; e < 8; e++) {
            float4 wv = ((const float4*)(gwt + e * DMODEL))[c * 64 + lane];
            acc[e] = fmaf(xv.x, wv.x, fmaf(xv.y, wv.y, fmaf(xv.z, wv.z, fmaf(xv.w, wv.w, acc[e]))));
        }
    }
#pragma unroll
    for (int o = 32; o; o >>= 1) {
#pragma unroll
        for (int e = 0; e < 8; e++) acc[e] += __shfl_xor(acc[e], o);
    }
    if (lane == 0) {
        int i0 = 0; float v0 = acc[0];
#pragma unroll
        for (int e = 1; e < 8; e++) if (acc[e] > v0) { v0 = acc[e]; i0 = e; }
        int i1 = -1; float v1 = -1e30f;
#pragma unroll
        for (int e = 0; e < 8; e++) if (e != i0 && acc[e] > v1) { v1 = acc[e]; i1 = e; }
        float ex = expf(v1 - v0);
        float g0 = 1.f / (1.f + ex);
        float g1 = ex / (1.f + ex);
        toke[2 * t] = i0; toke[2 * t + 1] = i1;
        tokg[2 * t] = g0; tokg[2 * t + 1] = g1;
        atomicAdd(&s_cnt[i0], 1); atomicAdd(&s_cnt[i1], 1); atomicAdd(&s_am[i0], 1);
        float p[8], sum = 0.f;
#pragma unroll
        for (int e = 0; e < 8; e++) { p[e] = expf(acc[e] - v0); sum += p[e]; }
        float inv = 1.f / sum;
#pragma unroll
        for (int e = 0; e < 8; e++) atomicAdd(&s_ps[e], p[e] * inv);
    }
    __syncthreads();
    if (tid < 8) {
        cnth[blockIdx.x * 8 + tid] = s_cnt[tid];
        amh[blockIdx.x * 8 + tid]  = s_am[tid];
        psh[blockIdx.x * 8 + tid]  = s_ps[tid];
    }
}

// single block: per-gate-block exclusive slot bases (scan), expert offsets, lb_loss.
__global__ void k_offsets(const int* __restrict__ cnth, const int* __restrict__ amh,
                          const float* __restrict__ psh, int* __restrict__ hdr,
                          int* __restrict__ bb, float* __restrict__ lb_out) {
    __shared__ int sc[8][256];
    __shared__ int sa[8][256];
    __shared__ float sp[8][256];
    __shared__ int sOff[8];
    int tid = threadIdx.x;
    int tc[8] = {0,0,0,0,0,0,0,0}, la[8] = {0,0,0,0,0,0,0,0};
    float lp[8] = {0.f,0.f,0.f,0.f,0.f,0.f,0.f,0.f};
    for (int j = 0; j < 8; j++) {
        int b = tid * 8 + j;
#pragma unroll
        for (int e = 0; e < 8; e++) { tc[e] += cnth[b * 8 + e]; la[e] += amh[b * 8 + e]; lp[e] += psh[b * 8 + e]; }
    }
#pragma unroll
    for (int e = 0; e < 8; e++) { sc[e][tid] = tc[e]; sa[e][tid] = la[e]; sp[e][tid] = lp[e]; }
    __syncthreads();
    for (int s = 1; s < 256; s <<= 1) {
        int add[8];
#pragma unroll
        for (int e = 0; e < 8; e++) add[e] = (tid >= s) ? sc[e][tid - s] : 0;
        __syncthreads();
#pragma unroll
        for (int e = 0; e < 8; e++) sc[e][tid] += add[e];
        __syncthreads();
    }
    for (int s = 128; s > 0; s >>= 1) {
        if (tid < s) {
#pragma unroll
            for (int e = 0; e < 8; e++) { sa[e][tid] += sa[e][tid + s]; sp[e][tid] += sp[e][tid + s]; }
        }
        __syncthreads();
    }
    if (tid == 0) {
        int run = 0; float lb = 0.f;
        for (int e = 0; e < 8; e++) {
            int c = sc[e][255];
            hdr[e] = c;
            hdr[16 + e] = run;
            int pad = ((c + 127) >> 7) << 7;
            hdr[24 + e] = pad;
            sOff[e] = run;
            run += pad;
            lb += ((float)sa[e][0] / (float)NTOK) * (sp[e][0] / (float)NTOK);
        }
        lb_out[0] = 8.f * lb;
    }
    __syncthreads();
    int excl[8];
#pragma unroll
    for (int e = 0; e < 8; e++) excl[e] = sOff[e] + sc[e][tid] - tc[e];
    for (int j = 0; j < 8; j++) {
        int b = tid * 8 + j;
#pragma unroll
        for (int e = 0; e < 8; e++) {
            bb[b * 8 + e] = excl[e];
            excl[e] += cnth[b * 8 + e];
        }
    }
}

// thread-per-token: deterministic slot = blockbase + rank; writes slot + inverse map
__global__ void k_scatter(const int* __restrict__ bb, const int* __restrict__ toke,
                          int* __restrict__ toks, int* __restrict__ inv) {
    int t = blockIdx.x * 256 + threadIdx.x;   // 0..8191
    int gb = t >> 2, k4 = t & 3;
    int a[8];
#pragma unroll
    for (int j = 0; j < 8; j++) a[j] = toke[gb * 8 + j];
    int e0 = a[2 * k4], e1 = a[2 * k4 + 1];
    int r0 = 0, r1 = 0;
    for (int j = 0; j < 2 * k4; j++) { r0 += (a[j] == e0); r1 += (a[j] == e1); }
    int s0 = bb[gb * 8 + e0] + r0;
    int s1 = bb[gb * 8 + e1] + r1;
    toks[2 * t] = s0; toks[2 * t + 1] = s1;
    inv[s0] = t; inv[s1] = t;
}

// block per 16-slot group: gather token rows, cast bf16, write Xg fragment-major (coalesced)
__global__ void k_gather(const float* __restrict__ x, const int* __restrict__ inv,
                         bf16* __restrict__ Xg) {
    int m16 = blockIdx.x;
    int tid = threadIdx.x, w = tid >> 6, lane = tid & 63;
    int quad = lane >> 4, fr = lane & 15;
    int t16 = (lane < 16) ? inv[m16 * 16 + lane] : -1;
    int tok = __shfl(t16, fr);
    bf16* dst = Xg + (size_t)m16 * 32 * 512 + lane * 8;
    for (int kb = w * 8; kb < w * 8 + 8; kb++) {
        bf16x8 pk;
        if (tok >= 0) {
            const float4* s = (const float4*)(x + (size_t)tok * DMODEL + kb * 32 + quad * 8);
            float4 u = s[0], v = s[1];
            pk[0] = (bf16)u.x; pk[1] = (bf16)u.y; pk[2] = (bf16)u.z; pk[3] = (bf16)u.w;
            pk[4] = (bf16)v.x; pk[5] = (bf16)v.y; pk[6] = (bf16)v.z; pk[7] = (bf16)v.w;
        } else {
#pragma unroll
            for (int j = 0; j < 8; j++) pk[j] = (bf16)0.f;
        }
        *(bf16x8*)(dst + (size_t)kb * 512) = pk;
    }
}

// fast GELU: x * sigmoid(1.5957691*(x + 0.044715 x^3)); |err vs exact| <= ~3e-4
__device__ __forceinline__ float gelu_fast(float x) {
    float x3 = x * x * x;
    float z = fmaf(0.0713548163f, x3, 1.5957691216f * x);
    float s = __builtin_amdgcn_rcpf(1.0f + __expf(-z));
    return x * s;
}

// ---- barrier-free register-streaming GEMM ----
// C[M,ND] = A[M,KD] @ W[ND,KD]^T + bias. A,W in fragment-major; no LDS in K-loop,
// 1-deep software pipeline, MFMA<->global_load interleaved (fine-grained vmcnt).
// GELU_BF16: gelu + write H fragment-major via LDS transpose; else f32 row-major.
template <int KD, int ND, bool GELU_BF16>
__global__ __launch_bounds__(256) void k_gemm(
    const bf16* __restrict__ Afm, const bf16* __restrict__ Wfm,
    const float* __restrict__ bias, void* __restrict__ Cbase,
    const int* __restrict__ hdr) {
    constexpr int KB = KD / 32;
    int flat = blockIdx.x;
    int g = flat % MTILES;
    int n = flat / MTILES;
    int row0 = g * 128;
    int total = hdr[16 + 7] + hdr[24 + 7];
    if (row0 >= total) return;
    int e = 0;
#pragma unroll
    for (int k = 1; k < 8; k++) e += (row0 >= hdr[16 + k]) ? 1 : 0;
    int nt = n * 128;

    int tid = threadIdx.x, w = tid >> 6, lane = tid & 63;
    int wm = (w & 1) * 64, wn = (w >> 1) * 64;
    int fr = lane & 15, quad = lane >> 4;

    const bf16* pA[4];
    const bf16* pB[4];
#pragma unroll
    for (int i = 0; i < 4; i++) {
        int m16 = ((row0 + wm) >> 4) + i;
        pA[i] = Afm + (size_t)m16 * KB * 512 + lane * 8;
        int n16 = ((nt + wn) >> 4) + i;
        pB[i] = Wfm + (size_t)e * ND * KD + (size_t)n16 * KB * 512 + lane * 8;
    }

    f32x4 acc[4][4] = {};
    bf16x8 a0[4], b0[4], a1[4], b1[4];
#pragma unroll
    for (int i = 0; i < 4; i++) { a0[i] = *(const bf16x8*)(pA[i]); b0[i] = *(const bf16x8*)(pB[i]); }

    for (int kb = 0; kb < KB; kb += 2) {
#pragma unroll
        for (int i = 0; i < 4; i++) {
            a1[i] = *(const bf16x8*)(pA[i] + (size_t)(kb + 1) * 512);
            b1[i] = *(const bf16x8*)(pB[i] + (size_t)(kb + 1) * 512);
        }
#pragma unroll
        for (int i = 0; i < 4; i++)
#pragma unroll
            for (int j = 0; j < 4; j++)
                acc[i][j] = __builtin_amdgcn_mfma_f32_16x16x32_bf16(a0[i], b0[j], acc[i][j], 0, 0, 0);
        if (kb + 2 < KB) {
#pragma unroll
            for (int i = 0; i < 4; i++) {
                a0[i] = *(const bf16x8*)(pA[i] + (size_t)(kb + 2) * 512);
                b0[i] = *(const bf16x8*)(pB[i] + (size_t)(kb + 2) * 512);
            }
        }
#pragma unroll
        for (int i = 0; i < 4; i++)
#pragma unroll
            for (int j = 0; j < 4; j++)
                acc[i][j] = __builtin_amdgcn_mfma_f32_16x16x32_bf16(a1[i], b1[j], acc[i][j], 0, 0, 0);
    }

    // epilogue: C/D layout col=lane&15, row=quad*4+reg  [verified m89/m91]
    if constexpr (GELU_BF16) {
        // gelu -> bf16 -> LDS transpose -> H fragment-major (coalesced bf16x8 lines)
        __shared__ bf16 Ct[128 * 136];
#pragma unroll
        for (int j = 0; j < 4; j++) {
            int lc = wn + j * 16 + fr;
            float bv = bias[e * ND + nt + lc];
#pragma unroll
            for (int i = 0; i < 4; i++) {
#pragma unroll
                for (int r = 0; r < 4; r++) {
                    int lr = wm + i * 16 + quad * 4 + r;
                    Ct[lr * 136 + lc] = (bf16)gelu_fast(acc[i][j][r] + bv);
                }
            }
        }
        __syncthreads();
        bf16* Hfm = (bf16*)Cbase;
        constexpr int KBH = ND / 32;
#pragma unroll
        for (int li = 0; li < 8; li++) {
            int line = w * 8 + li;
            int mg = line >> 2, kbl = line & 3;
            bf16x8 v = *(const bf16x8*)&Ct[(mg * 16 + fr) * 136 + kbl * 32 + quad * 8];
            size_t m16 = (size_t)(row0 >> 4) + mg;
            size_t kbG = (size_t)(nt >> 5) + kbl;
            *(bf16x8*)(Hfm + (m16 * KBH + kbG) * 512 + lane * 8) = v;
        }
    } else {
        float* Ob = (float*)Cbase;
#pragma unroll
        for (int j = 0; j < 4; j++) {
            int col = nt + wn + j * 16 + fr;
            float bv = bias[e * ND + col];
#pragma unroll
            for (int i = 0; i < 4; i++) {
#pragma unroll
                for (int r = 0; r < 4; r++) {
                    int row = row0 + wm + i * 16 + quad * 4 + r;
                    Ob[(size_t)row * ND + col] = acc[i][j][r] + bv;
                }
            }
        }
    }
}

// out[t] = g0*O[s0] + g1*O[s1]   (O already includes +b2)
__global__ void k_combine(const float* __restrict__ O, const int* __restrict__ toks,
                          const float* __restrict__ tokg, float* __restrict__ out) {
    int t = blockIdx.x;
    int s0 = toks[2 * t], s1 = toks[2 * t + 1];
    float g0 = tokg[2 * t], g1 = tokg[2 * t + 1];
    const float4* o0 = (const float4*)(O + (size_t)s0 * DMODEL);
    const float4* o1 = (const float4*)(O + (size_t)s1 * DMODEL);
    float4* dst = (float4*)(out + (size_t)t * DMODEL);
    int i = threadIdx.x;
    float4 a = o0[i], b = o1[i];
    float4 r;
    r.x = g0 * a.x + g1 * b.x;
    r.y = g0 * a.y + g1 * b.y;
    r.z = g0 * a.z + g1 * b.z;
    r.w = g0 * a.w + g1 * b.w;
    dst[i] = r;
}

// ---------------- launch ----------------
extern "C" void kernel_launch(void* const* d_in, const int* in_sizes, int n_in,
                              void* d_out, int out_size, void* d_ws, size_t ws_size,
                              hipStream_t stream) {
    const float* x   = (const float*)d_in[0];
    const float* gwt = (const float*)d_in[1];
    const float* w1  = (const float*)d_in[2];
    const float* b1  = (const float*)d_in[3];
    const float* w2  = (const float*)d_in[4];
    const float* b2  = (const float*)d_in[5];
    float* out = (float*)d_out;

    char* ws = (char*)d_ws;
    int*   hdr  = (int*)(ws + OFF_HDR);
    int*   cnth = (int*)(ws + OFF_CNTH);
    int*   amh  = (int*)(ws + OFF_AMH);
    float* psh  = (float*)(ws + OFF_PSH);
    int*   toke = (int*)(ws + OFF_TOKE);
    float* tokg = (float*)(ws + OFF_TOKG);
    int*   toks = (int*)(ws + OFF_TOKS);
    int*   bb   = (int*)(ws + OFF_BB);
    int*   inv  = (int*)(ws + OFF_INV);
    bf16*  Xg   = (bf16*)(ws + OFF_XG);
    bf16*  w1b  = (bf16*)(ws + OFF_W1B);
    bf16*  w2b  = (bf16*)(ws + OFF_W2B);
    bf16*  H    = (bf16*)(ws + OFF_H);
    float* O    = (float*)(ws + OFF_O);

    // inverse map = -1 (padding marker); 17*256 int4 == CAP ints exactly
    k_fillm1<<<17, 256, 0, stream>>>((int4*)inv);
    // weights -> bf16 fragment-major
    k_cvt_fm<DMODEL><<<NEXP * DFFN / 16, 256, 0, stream>>>(w1, w1b);   // w1: [E*DFF][D]
    k_cvt_fm<DFFN><<<NEXP * DMODEL / 16, 256, 0, stream>>>(w2, w2b);   // w2: [E*D][DFF]
    // gating
    k_gate<<<2048, 256, 0, stream>>>(x, gwt, cnth, amh, psh, toke, tokg);
    // offsets + block bases + lb_loss (written at out[NTOK*DMODEL])
    k_offsets<<<1, 256, 0, stream>>>(cnth, amh, psh, hdr, bb, out + (size_t)NTOK * DMODEL);
    // slot assignment (atomic-free) + inverse map
    k_scatter<<<32, 256, 0, stream>>>(bb, toke, toks, inv);
    // gather tokens -> Xg fragment-major (covers padding with zeros)
    k_gather<<<CAP / 16, 256, 0, stream>>>(x, inv, Xg);
    // GEMM1: H = gelu(Xg @ w1^T + b1)   [M x 4096], K=1024
    k_gemm<DMODEL, DFFN, true><<<MTILES * (DFFN / 128), 256, 0, stream>>>(Xg, w1b, b1, (void*)H, hdr);
    // GEMM2: O = H @ w2^T + b2          [M x 1024], K=4096
    k_gemm<DFFN, DMODEL, false><<<MTILES * (DMODEL / 128), 256, 0, stream>>>(H, w2b, b2, (void*)O, hdr);
    // combine
    k_combine<<<NTOK, 256, 0, stream>>>(O, toks, tokg, out);
}

// Round 6
// 968.015 us; speedup vs baseline: 1.0846x; 1.0846x over previous
//
#include <hip/hip_runtime.h>
#include <cstdint>
#include <cstddef>

// Problem constants
#define NEXP 8
#define NTOK 8192           // B*S = 4*2048
#define DMODEL 1024
#define DFFN 4096
#define CAP 17408           // 16384 assignments + 8*128 padding capacity
#define MTILES (CAP / 128)  // 136 = 8 XCDs x 17 contiguous m-tiles

typedef __bf16 bf16;
typedef bf16 bf16x8 __attribute__((ext_vector_type(8)));
typedef float f32x4 __attribute__((ext_vector_type(4)));

// ---------------- workspace layout (bytes) ----------------
static constexpr size_t OFF_HDR  = 0;                        // 64 ints: [0..8)cnt [16..24)off [24..32)padded
static constexpr size_t OFF_CNTH = 4096;                     // int[2048*8]
static constexpr size_t OFF_AMH  = 69632;                    // int[2048*8]
static constexpr size_t OFF_PSH  = 135168;                   // float[2048*8]
static constexpr size_t OFF_TOKE = 200704;                   // int[2*NTOK]
static constexpr size_t OFF_TOKG = 266240;                   // float[2*NTOK]
static constexpr size_t OFF_BB   = 331776;                   // int[2048*8]
static constexpr size_t OFF_GWS  = 397312;                   // float[CAP] per-slot gate weight
static constexpr size_t OFF_INV  = 471040;                   // int[CAP] slot->token (-1 = pad)
static constexpr size_t OFF_XG   = 544768;                   // bf16[CAP*DMODEL] row-major
static constexpr size_t OFF_W1B  = OFF_XG  + (size_t)CAP * DMODEL * 2;
static constexpr size_t OFF_W2B  = OFF_W1B + (size_t)NEXP * DFFN * DMODEL * 2;
static constexpr size_t OFF_H    = OFF_W2B + (size_t)NEXP * DMODEL * DFFN * 2;  // bf16[CAP*DFFN]

// ---------------- fused init: zero out[0..8M), zero Xg, inv = -1 ----------------
// grid = 8192 (out) + 8704 (Xg) + 17 (inv) = 16913 blocks x 256
__global__ void k_init(float4* __restrict__ outz, uint4* __restrict__ xg,
                       int4* __restrict__ inv) {
    int b = blockIdx.x, t = threadIdx.x;
    if (b < 8192) {
        outz[(size_t)b * 256 + t] = make_float4(0.f, 0.f, 0.f, 0.f);
    } else if (b < 8192 + 8704) {
        xg[(size_t)(b - 8192) * 256 + t] = make_uint4(0u, 0u, 0u, 0u);
    } else {
        inv[(size_t)(b - 16896) * 256 + t] = make_int4(-1, -1, -1, -1);
    }
}

__global__ void k_cvt(const float* __restrict__ s, bf16* __restrict__ d, int n8) {
    int i = blockIdx.x * 256 + threadIdx.x;
    if (i >= n8) return;
    const float4* sp = (const float4*)s;
    float4 a = sp[2 * i], b = sp[2 * i + 1];
    bf16x8 pk;
    pk[0] = (bf16)a.x; pk[1] = (bf16)a.y; pk[2] = (bf16)a.z; pk[3] = (bf16)a.w;
    pk[4] = (bf16)b.x; pk[5] = (bf16)b.y; pk[6] = (bf16)b.z; pk[7] = (bf16)b.w;
    ((bf16x8*)d)[i] = pk;
}

// wave-per-token gating: fp32 logits, top-2, full softmax partials, argmax hist
__global__ void k_gate(const float* __restrict__ x, const float* __restrict__ gwt,
                       int* __restrict__ cnth, int* __restrict__ amh, float* __restrict__ psh,
                       int* __restrict__ toke, float* __restrict__ tokg) {
    int tid = threadIdx.x, w = tid >> 6, lane = tid & 63;
    int t = blockIdx.x * 4 + w;
    __shared__ int s_cnt[8]; __shared__ int s_am[8]; __shared__ float s_ps[8];
    if (tid < 8) { s_cnt[tid] = 0; s_am[tid] = 0; s_ps[tid] = 0.f; }
    __syncthreads();
    float acc[8] = {0.f,0.f,0.f,0.f,0.f,0.f,0.f,0.f};
    const float4* xr = (const float4*)(x + (size_t)t * DMODEL);
#pragma unroll
    for (int c = 0; c < 4; c++) {
        float4 xv = xr[c * 64 + lane];
#pragma unroll
        for (int e = 0; e < 8; e++) {
            float4 wv = ((const float4*)(gwt + e * DMODEL))[c * 64 + lane];
            acc[e] = fmaf(xv.x, wv.x, fmaf(xv.y, wv.y, fmaf(xv.z, wv.z, fmaf(xv.w, wv.w, acc[e]))));
        }
    }
#pragma unroll
    for (int o = 32; o; o >>= 1) {
#pragma unroll
        for (int e = 0; e < 8; e++) acc[e] += __shfl_xor(acc[e], o);
    }
    if (lane == 0) {
        int i0 = 0; float v0 = acc[0];
#pragma unroll
        for (int e = 1; e < 8; e++) if (acc[e] > v0) { v0 = acc[e]; i0 = e; }
        int i1 = -1; float v1 = -1e30f;
#pragma unroll
        for (int e = 0; e < 8; e++) if (e != i0 && acc[e] > v1) { v1 = acc[e]; i1 = e; }
        float ex = expf(v1 - v0);
        float g0 = 1.f / (1.f + ex);
        float g1 = ex / (1.f + ex);
        toke[2 * t] = i0; toke[2 * t + 1] = i1;
        tokg[2 * t] = g0; tokg[2 * t + 1] = g1;
        atomicAdd(&s_cnt[i0], 1); atomicAdd(&s_cnt[i1], 1); atomicAdd(&s_am[i0], 1);
        float p[8], sum = 0.f;
#pragma unroll
        for (int e = 0; e < 8; e++) { p[e] = expf(acc[e] - v0); sum += p[e]; }
        float inv = 1.f / sum;
#pragma unroll
        for (int e = 0; e < 8; e++) atomicAdd(&s_ps[e], p[e] * inv);
    }
    __syncthreads();
    if (tid < 8) {
        cnth[blockIdx.x * 8 + tid] = s_cnt[tid];
        amh[blockIdx.x * 8 + tid]  = s_am[tid];
        psh[blockIdx.x * 8 + tid]  = s_ps[tid];
    }
}

// single block: per-gate-block exclusive slot bases (scan), expert offsets, lb_loss.
__global__ void k_offsets(const int* __restrict__ cnth, const int* __restrict__ amh,
                          const float* __restrict__ psh, int* __restrict__ hdr,
                          int* __restrict__ bb, float* __restrict__ lb_out) {
    __shared__ int sc[8][256];
    __shared__ int sa[8][256];
    __shared__ float sp[8][256];
    __shared__ int sOff[8];
    int tid = threadIdx.x;
    int tc[8] = {0,0,0,0,0,0,0,0}, la[8] = {0,0,0,0,0,0,0,0};
    float lp[8] = {0.f,0.f,0.f,0.f,0.f,0.f,0.f,0.f};
    for (int j = 0; j < 8; j++) {
        int b = tid * 8 + j;
#pragma unroll
        for (int e = 0; e < 8; e++) { tc[e] += cnth[b * 8 + e]; la[e] += amh[b * 8 + e]; lp[e] += psh[b * 8 + e]; }
    }
#pragma unroll
    for (int e = 0; e < 8; e++) { sc[e][tid] = tc[e]; sa[e][tid] = la[e]; sp[e][tid] = lp[e]; }
    __syncthreads();
    for (int s = 1; s < 256; s <<= 1) {
        int add[8];
#pragma unroll
        for (int e = 0; e < 8; e++) add[e] = (tid >= s) ? sc[e][tid - s] : 0;
        __syncthreads();
#pragma unroll
        for (int e = 0; e < 8; e++) sc[e][tid] += add[e];
        __syncthreads();
    }
    for (int s = 128; s > 0; s >>= 1) {
        if (tid < s) {
#pragma unroll
            for (int e = 0; e < 8; e++) { sa[e][tid] += sa[e][tid + s]; sp[e][tid] += sp[e][tid + s]; }
        }
        __syncthreads();
    }
    if (tid == 0) {
        int run = 0; float lb = 0.f;
        for (int e = 0; e < 8; e++) {
            int c = sc[e][255];
            hdr[e] = c;
            hdr[16 + e] = run;
            int pad = ((c + 127) >> 7) << 7;
            hdr[24 + e] = pad;
            sOff[e] = run;
            run += pad;
            lb += ((float)sa[e][0] / (float)NTOK) * (sp[e][0] / (float)NTOK);
        }
        lb_out[0] = 8.f * lb;
    }
    __syncthreads();
    int excl[8];
#pragma unroll
    for (int e = 0; e < 8; e++) excl[e] = sOff[e] + sc[e][tid] - tc[e];
    for (int j = 0; j < 8; j++) {
        int b = tid * 8 + j;
#pragma unroll
        for (int e = 0; e < 8; e++) {
            bb[b * 8 + e] = excl[e];
            excl[e] += cnth[b * 8 + e];
        }
    }
}

// wave-per-token: deterministic slot; writes inv/gws; gathers x row into Xg (bf16 row-major)
__global__ void k_scatter(const float* __restrict__ x, const int* __restrict__ bb,
                          const int* __restrict__ toke, const float* __restrict__ tokg,
                          int* __restrict__ inv, float* __restrict__ gws,
                          bf16* __restrict__ Xg) {
    int tid = threadIdx.x, w = tid >> 6, lane = tid & 63;
    int t = blockIdx.x * 4 + w;
    int a_e = (lane < 8) ? toke[blockIdx.x * 8 + lane] : 0;
    int e0 = __shfl(a_e, 2 * w), e1 = __shfl(a_e, 2 * w + 1);
    int r0 = 0, r1 = 0;
    for (int j = 0; j < 2 * w; j++) {
        int ej = __shfl(a_e, j);
        r0 += (ej == e0);
        r1 += (ej == e1);
    }
    int s0 = bb[blockIdx.x * 8 + e0] + r0;
    int s1 = bb[blockIdx.x * 8 + e1] + r1;
    if (lane == 0) {
        inv[s0] = t; inv[s1] = t;
        gws[s0] = tokg[2 * t]; gws[s1] = tokg[2 * t + 1];
    }
    const float4* xr = (const float4*)(x + (size_t)t * DMODEL);
    bf16* d0 = Xg + (size_t)s0 * DMODEL;
    bf16* d1 = Xg + (size_t)s1 * DMODEL;
#pragma unroll
    for (int c = 0; c < 2; c++) {
        int base = c * 512 + lane * 8;
        float4 u = xr[base >> 2], v = xr[(base >> 2) + 1];
        bf16x8 pk;
        pk[0] = (bf16)u.x; pk[1] = (bf16)u.y; pk[2] = (bf16)u.z; pk[3] = (bf16)u.w;
        pk[4] = (bf16)v.x; pk[5] = (bf16)v.y; pk[6] = (bf16)v.z; pk[7] = (bf16)v.w;
        *(bf16x8*)(d0 + base) = pk;
        *(bf16x8*)(d1 + base) = pk;
    }
}

// ---------------- grouped MFMA GEMM (R4 LDS recipe + expert-contiguous XCD map) ----------------
__device__ __forceinline__ void gll16(const bf16* g, bf16* l) {
    __builtin_amdgcn_global_load_lds((const __attribute__((address_space(1))) unsigned int*)g,
                                     (__attribute__((address_space(3))) unsigned int*)l, 16, 0, 0);
}

// fast GELU: x * sigmoid(1.5957691*(x + 0.044715 x^3)); |err vs exact| <= ~3e-4
__device__ __forceinline__ float gelu_fast(float x) {
    float x3 = x * x * x;
    float z = fmaf(0.0713548163f, x3, 1.5957691216f * x);
    float s = __builtin_amdgcn_rcpf(1.0f + __expf(-z));
    return x * s;
}

// C[M,ND] = A[M,KD] @ W[ND,KD]^T + bias  (rows globally contiguous across experts)
// XCD map: flat&7 = XCD gets contiguous m-band [17*xcd, 17*xcd+17) -> per-XCD B
// demand ~2 experts instead of 8 (lower MALL/HBM traffic + latency).
// GELU_BF16: gelu -> H bf16 row-major. Else: fused combine,
// atomicAdd(out[tok], gw*(v+bias)) per element (2 slots/token, distinct addrs).
template <int KD, int ND, bool GELU_BF16>
__global__ __launch_bounds__(256) void k_gemm(
    const bf16* __restrict__ Abase, const bf16* __restrict__ Wbase,
    const float* __restrict__ bias, void* __restrict__ Cbase,
    const int* __restrict__ hdr, const int* __restrict__ inv,
    const float* __restrict__ gws) {
    int flat = blockIdx.x;
    int rest = flat >> 3;
    int g = (flat & 7) * 17 + (rest % 17);
    int n = rest / 17;
    int row0 = g * 128;
    int total = hdr[16 + 7] + hdr[24 + 7];   // total padded rows
    if (row0 >= total) return;
    int e = 0;
#pragma unroll
    for (int k = 1; k < 8; k++) e += (row0 >= hdr[16 + k]) ? 1 : 0;
    int nt = n * 128;

    const bf16* A = Abase + (size_t)row0 * KD;
    const bf16* W = Wbase + (size_t)e * ND * KD + (size_t)nt * KD;

    __shared__ bf16 As[128 * 64];
    __shared__ bf16 Bs[128 * 64];
    __shared__ int s_inv[128];
    __shared__ float s_gw[128];

    int tid = threadIdx.x, w = tid >> 6, lane = tid & 63;
    int lrow = lane >> 3;                         // 0..7 within 8-row staging group
    int lcolswz = ((lane & 7) ^ lrow) * 8;        // swizzled source chunk
    int wm = (w & 1) * 64, wn = (w >> 1) * 64;
    int fr = lane & 15, quad = lane >> 4;
    int swz = quad ^ (fr & 7);                    // fragment-read chunk xor base

    f32x4 acc[4][4] = {};

    for (int k0 = 0; k0 < KD; k0 += 64) {
#pragma unroll
        for (int i = 0; i < 4; i++) {
            int rb = w * 32 + i * 8;
            gll16(A + (size_t)(rb + lrow) * KD + k0 + lcolswz, &As[rb * 64]);
            gll16(W + (size_t)(rb + lrow) * KD + k0 + lcolswz, &Bs[rb * 64]);
        }
        __syncthreads();
#pragma unroll
        for (int kk = 0; kk < 64; kk += 32) {
            int coff = (swz ^ (kk >> 3)) * 8;
            bf16x8 af[4], bfr[4];
#pragma unroll
            for (int i = 0; i < 4; i++) af[i]  = *(const bf16x8*)&As[(wm + i * 16 + fr) * 64 + coff];
#pragma unroll
            for (int j = 0; j < 4; j++) bfr[j] = *(const bf16x8*)&Bs[(wn + j * 16 + fr) * 64 + coff];
#pragma unroll
            for (int i = 0; i < 4; i++)
#pragma unroll
                for (int j = 0; j < 4; j++)
                    acc[i][j] = __builtin_amdgcn_mfma_f32_16x16x32_bf16(af[i], bfr[j], acc[i][j], 0, 0, 0);
        }
        __syncthreads();
    }

    // epilogue: C/D layout col=lane&15, row=quad*4+reg  [verified m89/m91]
    if constexpr (GELU_BF16) {
#pragma unroll
        for (int j = 0; j < 4; j++) {
            int col = nt + wn + j * 16 + fr;
            float bv = bias[e * ND + col];
#pragma unroll
            for (int i = 0; i < 4; i++) {
#pragma unroll
                for (int r = 0; r < 4; r++) {
                    int row = row0 + wm + i * 16 + quad * 4 + r;
                    ((bf16*)Cbase)[(size_t)row * ND + col] = (bf16)gelu_fast(acc[i][j][r] + bv);
                }
            }
        }
    } else {
        if (tid < 128) { s_inv[tid] = inv[row0 + tid]; s_gw[tid] = gws[row0 + tid]; }
        __syncthreads();
        float* outp = (float*)Cbase;
#pragma unroll
        for (int j = 0; j < 4; j++) {
            int col = nt + wn + j * 16 + fr;
            float bv = bias[e * ND + col];
#pragma unroll
            for (int i = 0; i < 4; i++) {
#pragma unroll
                for (int r = 0; r < 4; r++) {
                    int lr = wm + i * 16 + quad * 4 + r;
                    int tok = s_inv[lr];
                    if (tok >= 0)
                        atomicAdd(outp + (size_t)tok * ND + col, s_gw[lr] * (acc[i][j][r] + bv));
                }
            }
        }
    }
}

// ---------------- launch ----------------
extern "C" void kernel_launch(void* const* d_in, const int* in_sizes, int n_in,
                              void* d_out, int out_size, void* d_ws, size_t ws_size,
                              hipStream_t stream) {
    const float* x   = (const float*)d_in[0];
    const float* gwt = (const float*)d_in[1];
    const float* w1  = (const float*)d_in[2];
    const float* b1  = (const float*)d_in[3];
    const float* w2  = (const float*)d_in[4];
    const float* b2  = (const float*)d_in[5];
    float* out = (float*)d_out;

    char* ws = (char*)d_ws;
    int*   hdr  = (int*)(ws + OFF_HDR);
    int*   cnth = (int*)(ws + OFF_CNTH);
    int*   amh  = (int*)(ws + OFF_AMH);
    float* psh  = (float*)(ws + OFF_PSH);
    int*   toke = (int*)(ws + OFF_TOKE);
    float* tokg = (float*)(ws + OFF_TOKG);
    int*   bb   = (int*)(ws + OFF_BB);
    float* gws  = (float*)(ws + OFF_GWS);
    int*   inv  = (int*)(ws + OFF_INV);
    bf16*  Xg   = (bf16*)(ws + OFF_XG);
    bf16*  w1b  = (bf16*)(ws + OFF_W1B);
    bf16*  w2b  = (bf16*)(ws + OFF_W2B);
    bf16*  H    = (bf16*)(ws + OFF_H);

    // fused init: zero out[0..8M), zero Xg (padding rows), inv = -1
    k_init<<<16913, 256, 0, stream>>>((float4*)out, (uint4*)Xg, (int4*)inv);
    // convert weights to bf16 (elementwise, fast)
    k_cvt<<<16384, 256, 0, stream>>>(w1, w1b, 4194304);
    k_cvt<<<16384, 256, 0, stream>>>(w2, w2b, 4194304);
    // gating
    k_gate<<<2048, 256, 0, stream>>>(x, gwt, cnth, amh, psh, toke, tokg);
    // offsets + block bases + lb_loss (written at out[NTOK*DMODEL], after k_init zeroing)
    k_offsets<<<1, 256, 0, stream>>>(cnth, amh, psh, hdr, bb, out + (size_t)NTOK * DMODEL);
    // scatter tokens (atomic-free) + inv/gws
    k_scatter<<<2048, 256, 0, stream>>>(x, bb, toke, tokg, inv, gws, Xg);
    // GEMM1: H = gelu(Xg @ w1^T + b1)   [M x 4096], K=1024
    k_gemm<DMODEL, DFFN, true><<<MTILES * (DFFN / 128), 256, 0, stream>>>(
        Xg, w1b, b1, (void*)H, hdr, nullptr, nullptr);
    // GEMM2 + fused combine: out[tok] += gw * (H @ w2^T + b2)   [M x 1024], K=4096
    k_gemm<DFFN, DMODEL, false><<<MTILES * (DMODEL / 128), 256, 0, stream>>>(
        H, w2b, b2, (void*)out, hdr, inv, gws);
}